// Round 1
// baseline (12996.465 us; speedup 1.0000x reference)
//
#include <hip/hip_runtime.h>
#include <cstdint>
#include <cstddef>

#define NN 100000
#define EE 200000
#define AA 400000
#define DD 128
#define LL 5

// RBF constants (module-level constants in the reference, not inputs)
__constant__ float c_bf_start[8] = {0.f, 0.f, 3.f, 0.f, 0.f, 0.f, 0.f, 0.f};
__constant__ float c_bf_step[8]  = {0.1f, 0.05f, 0.3f, 0.05f, 0.05f, 0.05f, 0.5f, 0.05f};
__constant__ int   c_bf_cnt[8]   = {20, 20, 30, 20, 20, 20, 20, 20};
__constant__ float c_bf_gam[8]   = {10.f, 1.f, 1.f, 1.f, 1.f, 1.f, 2.f, 1.f};

// ---------------- atom embedding: h[n,d] = sum_f atab[f, x[n,f], d] ----------------
__global__ __launch_bounds__(128) void k_atom_embed(
    const int* __restrict__ xa, const float* __restrict__ tab, float* __restrict__ h)
{
  __shared__ int idx[9];
  int n = blockIdx.x, d = threadIdx.x;
  if (d < 9) idx[d] = xa[n * 9 + d];
  __syncthreads();
  float s = 0.f;
#pragma unroll
  for (int f = 0; f < 9; ++f) s += tab[(f * 124 + idx[f]) * DD + d];
  h[(size_t)n * DD + d] = s;
}

// ---------------- bond embedding: int-embed + RBF(240) @ W + biases ----------------
// 32 edges/block, 256 threads, each thread: 2 edges x 8 cols
__global__ __launch_bounds__(256) void k_bond_embed(
    const float* __restrict__ xf, const int* __restrict__ eai,
    const float* __restrict__ btab,   // [3,12,128] this layer
    const float* __restrict__ bfW,    // [240,128]  this layer
    const float* __restrict__ bfb,    // [8,128]    this layer
    float* __restrict__ out)          // [E,128]
{
  __shared__ float rbf[32][240];
  __shared__ float xfs[32][8];
  __shared__ int   ii[32][3];
  int tid = threadIdx.x;
  int e0 = blockIdx.x * 32;
  { int e = tid >> 3, f = tid & 7; xfs[e][f] = xf[(size_t)(e0 + e) * 8 + f]; }
  if (tid < 96) { int e = tid / 3, f = tid - 3 * e; ii[e][f] = eai[(size_t)(e0 + e) * 3 + f]; }
  __syncthreads();
#pragma unroll
  for (int i = 0; i < 30; ++i) {
    int j = tid + i * 256;
    int e = j / 240;
    int k = j - e * 240;
    int f = k / 30;
    int c = k - f * 30;
    float x = xfs[e][f];
    float cen = c_bf_start[f] + c_bf_step[f] * (float)c;
    float dx = x - cen;
    rbf[e][k] = (c < c_bf_cnt[f]) ? __expf(-c_bf_gam[f] * dx * dx) : 0.f;
  }
  __syncthreads();
  int cg = tid & 15, eg = tid >> 4;
  int c0 = cg * 8;
  int eb = eg * 2;
  float acc[2][8];
  {
    float bs[8] = {0, 0, 0, 0, 0, 0, 0, 0};
#pragma unroll
    for (int f = 0; f < 8; ++f) {
      float4 v0 = *(const float4*)&bfb[f * DD + c0];
      float4 v1 = *(const float4*)&bfb[f * DD + c0 + 4];
      bs[0] += v0.x; bs[1] += v0.y; bs[2] += v0.z; bs[3] += v0.w;
      bs[4] += v1.x; bs[5] += v1.y; bs[6] += v1.z; bs[7] += v1.w;
    }
#pragma unroll
    for (int e2 = 0; e2 < 2; ++e2) {
#pragma unroll
      for (int j = 0; j < 8; ++j) acc[e2][j] = bs[j];
#pragma unroll
      for (int f = 0; f < 3; ++f) {
        int row = f * 12 + ii[eb + e2][f];
        float4 v0 = *(const float4*)&btab[row * DD + c0];
        float4 v1 = *(const float4*)&btab[row * DD + c0 + 4];
        acc[e2][0] += v0.x; acc[e2][1] += v0.y; acc[e2][2] += v0.z; acc[e2][3] += v0.w;
        acc[e2][4] += v1.x; acc[e2][5] += v1.y; acc[e2][6] += v1.z; acc[e2][7] += v1.w;
      }
    }
  }
#pragma unroll 2
  for (int k = 0; k < 240; k += 4) {
    float4 w0[4], w1[4];
#pragma unroll
    for (int kk = 0; kk < 4; ++kk) {
      w0[kk] = *(const float4*)&bfW[(k + kk) * DD + c0];
      w1[kk] = *(const float4*)&bfW[(k + kk) * DD + c0 + 4];
    }
#pragma unroll
    for (int e2 = 0; e2 < 2; ++e2) {
      float4 r4 = *(const float4*)&rbf[eb + e2][k];
      float rr[4] = {r4.x, r4.y, r4.z, r4.w};
#pragma unroll
      for (int kk = 0; kk < 4; ++kk) {
        acc[e2][0] = fmaf(rr[kk], w0[kk].x, acc[e2][0]);
        acc[e2][1] = fmaf(rr[kk], w0[kk].y, acc[e2][1]);
        acc[e2][2] = fmaf(rr[kk], w0[kk].z, acc[e2][2]);
        acc[e2][3] = fmaf(rr[kk], w0[kk].w, acc[e2][3]);
        acc[e2][4] = fmaf(rr[kk], w1[kk].x, acc[e2][4]);
        acc[e2][5] = fmaf(rr[kk], w1[kk].y, acc[e2][5]);
        acc[e2][6] = fmaf(rr[kk], w1[kk].z, acc[e2][6]);
        acc[e2][7] = fmaf(rr[kk], w1[kk].w, acc[e2][7]);
      }
    }
  }
#pragma unroll
  for (int e2 = 0; e2 < 2; ++e2) {
    int e = e0 + eb + e2;
    *(float4*)&out[(size_t)e * DD + c0]     = make_float4(acc[e2][0], acc[e2][1], acc[e2][2], acc[e2][3]);
    *(float4*)&out[(size_t)e * DD + c0 + 4] = make_float4(acc[e2][4], acc[e2][5], acc[e2][6], acc[e2][7]);
  }
}

// ---------------- angle embed + message + scatter (bond-angle graph) ----------------
// msg = relu(x[src_b] + angle_emb); atomicAdd into pre[dst_b]
__global__ __launch_bounds__(256) void k_angle_msg(
    const float* __restrict__ xba, const int* __restrict__ eib,
    const float* __restrict__ Wa,  const float* __restrict__ ba,
    const float* __restrict__ Wr,  const float* __restrict__ br,
    const float* __restrict__ x,   float* __restrict__ pre)
{
  __shared__ float arbf[32][32];
  __shared__ float x0s[32];
  __shared__ float xrest[32][5];
  __shared__ int sb[32], db[32];
  int tid = threadIdx.x;
  int a0 = blockIdx.x * 32;
  if (tid < 192) {
    int e = tid / 6, f = tid - 6 * e;
    float v = xba[(size_t)(a0 + e) * 6 + f];
    if (f == 0) x0s[e] = v; else xrest[e][f - 1] = v;
  } else if (tid < 224) {
    sb[tid - 192] = eib[a0 + (tid - 192)];
  } else {
    db[tid - 224] = eib[AA + a0 + (tid - 224)];
  }
  __syncthreads();
#pragma unroll
  for (int i = 0; i < 4; ++i) {
    int j = tid + i * 256;
    int e = j >> 5, c = j & 31;
    float dx = x0s[e] - 0.1f * (float)c;
    arbf[e][c] = __expf(-10.f * dx * dx);
  }
  __syncthreads();
  int cg = tid & 15, eg = tid >> 4;
  int c0 = cg * 8, eb = eg * 2;
  float acc[2][8];
  {
    float4 v0 = *(const float4*)&ba[c0];
    float4 v1 = *(const float4*)&ba[c0 + 4];
    float4 u0 = *(const float4*)&br[c0];
    float4 u1 = *(const float4*)&br[c0 + 4];
#pragma unroll
    for (int e2 = 0; e2 < 2; ++e2) {
      acc[e2][0] = v0.x + u0.x; acc[e2][1] = v0.y + u0.y;
      acc[e2][2] = v0.z + u0.z; acc[e2][3] = v0.w + u0.w;
      acc[e2][4] = v1.x + u1.x; acc[e2][5] = v1.y + u1.y;
      acc[e2][6] = v1.z + u1.z; acc[e2][7] = v1.w + u1.w;
    }
  }
#pragma unroll
  for (int c = 0; c < 32; c += 4) {
    float4 w0[4], w1[4];
#pragma unroll
    for (int kk = 0; kk < 4; ++kk) {
      w0[kk] = *(const float4*)&Wa[(c + kk) * DD + c0];
      w1[kk] = *(const float4*)&Wa[(c + kk) * DD + c0 + 4];
    }
#pragma unroll
    for (int e2 = 0; e2 < 2; ++e2) {
      float4 r4 = *(const float4*)&arbf[eb + e2][c];
      float rr[4] = {r4.x, r4.y, r4.z, r4.w};
#pragma unroll
      for (int kk = 0; kk < 4; ++kk) {
        acc[e2][0] = fmaf(rr[kk], w0[kk].x, acc[e2][0]);
        acc[e2][1] = fmaf(rr[kk], w0[kk].y, acc[e2][1]);
        acc[e2][2] = fmaf(rr[kk], w0[kk].z, acc[e2][2]);
        acc[e2][3] = fmaf(rr[kk], w0[kk].w, acc[e2][3]);
        acc[e2][4] = fmaf(rr[kk], w1[kk].x, acc[e2][4]);
        acc[e2][5] = fmaf(rr[kk], w1[kk].y, acc[e2][5]);
        acc[e2][6] = fmaf(rr[kk], w1[kk].z, acc[e2][6]);
        acc[e2][7] = fmaf(rr[kk], w1[kk].w, acc[e2][7]);
      }
    }
  }
#pragma unroll
  for (int j2 = 0; j2 < 5; ++j2) {
    float4 w0 = *(const float4*)&Wr[j2 * DD + c0];
    float4 w1 = *(const float4*)&Wr[j2 * DD + c0 + 4];
#pragma unroll
    for (int e2 = 0; e2 < 2; ++e2) {
      float xr = xrest[eb + e2][j2];
      acc[e2][0] = fmaf(xr, w0.x, acc[e2][0]);
      acc[e2][1] = fmaf(xr, w0.y, acc[e2][1]);
      acc[e2][2] = fmaf(xr, w0.z, acc[e2][2]);
      acc[e2][3] = fmaf(xr, w0.w, acc[e2][3]);
      acc[e2][4] = fmaf(xr, w1.x, acc[e2][4]);
      acc[e2][5] = fmaf(xr, w1.y, acc[e2][5]);
      acc[e2][6] = fmaf(xr, w1.z, acc[e2][6]);
      acc[e2][7] = fmaf(xr, w1.w, acc[e2][7]);
    }
  }
#pragma unroll
  for (int e2 = 0; e2 < 2; ++e2) {
    int a = eb + e2;
    int s = sb[a], d = db[a];
    float4 xv0 = *(const float4*)&x[(size_t)s * DD + c0];
    float4 xv1 = *(const float4*)&x[(size_t)s * DD + c0 + 4];
    float m[8];
    m[0] = fmaxf(xv0.x + acc[e2][0], 0.f);
    m[1] = fmaxf(xv0.y + acc[e2][1], 0.f);
    m[2] = fmaxf(xv0.z + acc[e2][2], 0.f);
    m[3] = fmaxf(xv0.w + acc[e2][3], 0.f);
    m[4] = fmaxf(xv1.x + acc[e2][4], 0.f);
    m[5] = fmaxf(xv1.y + acc[e2][5], 0.f);
    m[6] = fmaxf(xv1.z + acc[e2][6], 0.f);
    m[7] = fmaxf(xv1.w + acc[e2][7], 0.f);
    float* p = &pre[(size_t)d * DD + c0];
#pragma unroll
    for (int j = 0; j < 8; ++j) atomicAdd(&p[j], m[j]);
  }
}

// ---------------- atom message: msg = relu(h[src]+h_ba[e]); scatter to pre[dst] ----
__global__ __launch_bounds__(256) void k_atom_msg(
    const int* __restrict__ ei, const float* __restrict__ h,
    const float* __restrict__ hB, float* __restrict__ pre)
{
  int gid = blockIdx.x * 256 + threadIdx.x;   // E*128 total, exact
  int e = gid >> 7, d = gid & 127;
  int s = ei[e], t = ei[EE + e];
  float m = fmaxf(h[(size_t)s * DD + d] + hB[(size_t)e * DD + d], 0.f);
  atomicAdd(&pre[(size_t)t * DD + d], m);
}

// ---------------- pre = (1+eps)*x ----------------
__global__ __launch_bounds__(256) void k_scale_init(
    const float* __restrict__ x, float* __restrict__ y, const float* __restrict__ eps_l)
{
  int i = blockIdx.x * 256 + threadIdx.x;
  y[i] = (1.f + *eps_l) * x[i];
}

// ---------------- x = relu(x*scale[d] + shift[d]) ----------------
__global__ __launch_bounds__(256) void k_bn_relu(
    float* __restrict__ x, const float* __restrict__ scale, const float* __restrict__ shift)
{
  int i = blockIdx.x * 256 + threadIdx.x;
  int d = i & 127;
  x[i] = fmaxf(x[i] * scale[d] + shift[d], 0.f);
}

// ---------------- BN finalize: scale/shift from sums ----------------
__global__ __launch_bounds__(128) void k_bn_finalize(
    const float* __restrict__ sum, const float* __restrict__ sq,
    const float* __restrict__ g, const float* __restrict__ be,
    float* __restrict__ scale, float* __restrict__ shift, float invM)
{
  int c = threadIdx.x;
  float mean = sum[c] * invM;
  float var = sq[c] * invM - mean * mean;
  float s = g[c] / sqrtf(var + 1e-5f);
  scale[c] = s;
  shift[c] = be[c] - mean * s;
}

// ---------------- GEMM [M,128]@[128,128]+bias, optional input-affine-relu, out stats
// 128x128 block tile, 256 threads, 8x8 micro-tile
template<bool IN_AFFINE, bool OUT_STATS>
__global__ __launch_bounds__(256) void k_gemm(
    const float* __restrict__ A, const float* __restrict__ W,
    const float* __restrict__ bias, float* __restrict__ out,
    const float* __restrict__ iscale, const float* __restrict__ ishift,
    float* __restrict__ osum, float* __restrict__ osq, int M)
{
  __shared__ float As[128][33];
  __shared__ float Bs[32][128];
  __shared__ float redsum[128];
  __shared__ float redsq[128];
  int tid = threadIdx.x;
  int row0 = blockIdx.x * 128;
  int cg = tid & 15, rg = tid >> 4;
  int c0 = cg * 8, r0 = rg * 8;
  float acc[8][8];
#pragma unroll
  for (int i = 0; i < 8; ++i)
#pragma unroll
    for (int j = 0; j < 8; ++j) acc[i][j] = 0.f;

  for (int kc = 0; kc < 4; ++kc) {
    int k0 = kc * 32;
#pragma unroll
    for (int i = 0; i < 4; ++i) {
      int vid = tid + i * 256;
      int r = vid >> 3;
      int k4 = (vid & 7) * 4;
      int grow = row0 + r;
      float4 v = make_float4(0.f, 0.f, 0.f, 0.f);
      if (grow < M) v = *(const float4*)&A[(size_t)grow * DD + k0 + k4];
      if (IN_AFFINE) {
        float4 sc = *(const float4*)&iscale[k0 + k4];
        float4 sh = *(const float4*)&ishift[k0 + k4];
        v.x = fmaxf(fmaf(v.x, sc.x, sh.x), 0.f);
        v.y = fmaxf(fmaf(v.y, sc.y, sh.y), 0.f);
        v.z = fmaxf(fmaf(v.z, sc.z, sh.z), 0.f);
        v.w = fmaxf(fmaf(v.w, sc.w, sh.w), 0.f);
      }
      As[r][k4] = v.x; As[r][k4 + 1] = v.y; As[r][k4 + 2] = v.z; As[r][k4 + 3] = v.w;
    }
#pragma unroll
    for (int i = 0; i < 4; ++i) {
      int vid = tid + i * 256;
      int kl = vid >> 5;
      int c4 = (vid & 31) * 4;
      *(float4*)&Bs[kl][c4] = *(const float4*)&W[(size_t)(k0 + kl) * DD + c4];
    }
    __syncthreads();
#pragma unroll 4
    for (int kl = 0; kl < 32; ++kl) {
      float4 b0 = *(const float4*)&Bs[kl][c0];
      float4 b1 = *(const float4*)&Bs[kl][c0 + 4];
      float a[8];
#pragma unroll
      for (int i = 0; i < 8; ++i) a[i] = As[r0 + i][kl];
#pragma unroll
      for (int i = 0; i < 8; ++i) {
        acc[i][0] = fmaf(a[i], b0.x, acc[i][0]);
        acc[i][1] = fmaf(a[i], b0.y, acc[i][1]);
        acc[i][2] = fmaf(a[i], b0.z, acc[i][2]);
        acc[i][3] = fmaf(a[i], b0.w, acc[i][3]);
        acc[i][4] = fmaf(a[i], b1.x, acc[i][4]);
        acc[i][5] = fmaf(a[i], b1.y, acc[i][5]);
        acc[i][6] = fmaf(a[i], b1.z, acc[i][6]);
        acc[i][7] = fmaf(a[i], b1.w, acc[i][7]);
      }
    }
    __syncthreads();
  }
  if (OUT_STATS) {
    if (tid < 128) { redsum[tid] = 0.f; redsq[tid] = 0.f; }
    __syncthreads();
  }
  float4 bv0 = *(const float4*)&bias[c0];
  float4 bv1 = *(const float4*)&bias[c0 + 4];
  float csum[8], csq[8];
#pragma unroll
  for (int j = 0; j < 8; ++j) { csum[j] = 0.f; csq[j] = 0.f; }
#pragma unroll
  for (int i = 0; i < 8; ++i) {
    int grow = row0 + r0 + i;
    if (grow < M) {
      float o[8];
      o[0] = acc[i][0] + bv0.x; o[1] = acc[i][1] + bv0.y;
      o[2] = acc[i][2] + bv0.z; o[3] = acc[i][3] + bv0.w;
      o[4] = acc[i][4] + bv1.x; o[5] = acc[i][5] + bv1.y;
      o[6] = acc[i][6] + bv1.z; o[7] = acc[i][7] + bv1.w;
      *(float4*)&out[(size_t)grow * DD + c0]     = make_float4(o[0], o[1], o[2], o[3]);
      *(float4*)&out[(size_t)grow * DD + c0 + 4] = make_float4(o[4], o[5], o[6], o[7]);
      if (OUT_STATS) {
#pragma unroll
        for (int j = 0; j < 8; ++j) { csum[j] += o[j]; csq[j] += o[j] * o[j]; }
      }
    }
  }
  if (OUT_STATS) {
#pragma unroll
    for (int j = 0; j < 8; ++j) {
      atomicAdd(&redsum[c0 + j], csum[j]);
      atomicAdd(&redsq[c0 + j],  csq[j]);
    }
    __syncthreads();
    if (tid < 128) {
      atomicAdd(&osum[tid], redsum[tid]);
      atomicAdd(&osq[tid],  redsq[tid]);
    }
  }
}

extern "C" void kernel_launch(void* const* d_in, const int* in_sizes, int n_in,
                              void* d_out, int out_size, void* d_ws, size_t ws_size,
                              hipStream_t stream)
{
  (void)in_sizes; (void)n_in; (void)out_size; (void)ws_size;
  const int*   x_atom = (const int*)  d_in[0];
  const int*   ei     = (const int*)  d_in[1];
  const int*   eai    = (const int*)  d_in[2];
  const int*   eib    = (const int*)  d_in[3];
  const float* xf     = (const float*)d_in[4];
  const float* xba    = (const float*)d_in[5];
  const float* atab   = (const float*)d_in[6];
  const float* btab   = (const float*)d_in[7];
  const float* bfW    = (const float*)d_in[8];
  const float* bfb    = (const float*)d_in[9];
  const float* Wang   = (const float*)d_in[10];
  const float* bang   = (const float*)d_in[11];
  const float* Wrest  = (const float*)d_in[12];
  const float* brest  = (const float*)d_in[13];
  const float* eps_a  = (const float*)d_in[14];
  const float* W1_a   = (const float*)d_in[15];
  const float* b1_a   = (const float*)d_in[16];
  const float* bng_a  = (const float*)d_in[17];
  const float* bnb_a  = (const float*)d_in[18];
  const float* W2_a   = (const float*)d_in[19];
  const float* b2_a   = (const float*)d_in[20];
  const float* eps_g  = (const float*)d_in[21];
  const float* W1_g   = (const float*)d_in[22];
  const float* b1_g   = (const float*)d_in[23];
  const float* bng_g  = (const float*)d_in[24];
  const float* bnb_g  = (const float*)d_in[25];
  const float* W2_g   = (const float*)d_in[26];
  const float* b2_g   = (const float*)d_in[27];
  const float* obng_a = (const float*)d_in[28];
  const float* obnb_a = (const float*)d_in[29];
  const float* obng_b = (const float*)d_in[30];
  const float* obnb_b = (const float*)d_in[31];

  float* out_a = (float*)d_out;                 // final h [N,128]
  float* out_b = out_a + (size_t)NN * DD;       // final h_ba [E,128]
  float* ws = (float*)d_ws;
  const size_t ED = (size_t)EE * DD, ND = (size_t)NN * DD;
  // ws layout (358.4 MB): preB | T (also bond-embed scratch) | hB0 | hA0 | stats
  float* preB  = ws;              // [E,128] pre-MLP accumulator (atom uses first N rows)
  float* T     = ws + ED;         // [E,128] GEMM1 output / bond-embed buffer (disjoint lifetimes)
  float* hB0   = ws + 2 * ED;     // [E,128] bond state ping
  float* hA0   = ws + 3 * ED;     // [N,128] atom state ping
  float* stats = ws + 3 * ED + ND;
  float* sumA = stats,        *sqA = stats + 128;
  float* sumB = stats + 256,  *sqB = stats + 384;
  float* scA  = stats + 512,  *shA = stats + 640;
  float* scB  = stats + 768,  *shB = stats + 896;

  // initial embeddings
  k_atom_embed<<<NN, 128, 0, stream>>>(x_atom, atab, hA0);
  k_bond_embed<<<EE / 32, 256, 0, stream>>>(xf, eai, btab, bfW, bfb, hB0);

  float* hA_cur = hA0;
  float* hB_cur = hB0;
  for (int l = 0; l < LL; ++l) {
    float* hA_nxt = (l & 1) ? hA0 : out_a;   // l=4 lands in d_out
    float* hB_nxt = (l & 1) ? hB0 : out_b;
    const bool obn = (l < LL - 1);

    // ---- atom GIN conv ----
    hipMemsetAsync(stats, 0, 512 * sizeof(float), stream);
    k_scale_init<<<ND / 256, 256, 0, stream>>>(hA_cur, preB, eps_a + l);
    k_atom_msg<<<ED / 256, 256, 0, stream>>>(ei, hA_cur, hB_cur, preB);
    k_gemm<false, true><<<(NN + 127) / 128, 256, 0, stream>>>(
        preB, W1_a + (size_t)l * DD * DD, b1_a + l * DD, T, nullptr, nullptr, sumA, sqA, NN);
    k_bn_finalize<<<1, 128, 0, stream>>>(sumA, sqA, bng_a + l * DD, bnb_a + l * DD, scA, shA, 1.f / NN);
    if (obn) {
      k_gemm<true, true><<<(NN + 127) / 128, 256, 0, stream>>>(
          T, W2_a + (size_t)l * DD * DD, b2_a + l * DD, hA_nxt, scA, shA, sumB, sqB, NN);
      k_bn_finalize<<<1, 128, 0, stream>>>(sumB, sqB, obng_a + l * DD, obnb_a + l * DD, scB, shB, 1.f / NN);
      k_bn_relu<<<ND / 256, 256, 0, stream>>>(hA_nxt, scB, shB);
    } else {
      k_gemm<true, false><<<(NN + 127) / 128, 256, 0, stream>>>(
          T, W2_a + (size_t)l * DD * DD, b2_a + l * DD, hA_nxt, scA, shA, nullptr, nullptr, NN);
    }

    // ---- bond GIN conv ----
    hipMemsetAsync(stats, 0, 512 * sizeof(float), stream);
    k_bond_embed<<<EE / 32, 256, 0, stream>>>(
        xf, eai, btab + (size_t)(l + 1) * 3 * 12 * DD,
        bfW + (size_t)(l + 1) * 240 * DD, bfb + (size_t)(l + 1) * 8 * DD, T);
    k_scale_init<<<ED / 256, 256, 0, stream>>>(T, preB, eps_g + l);
    k_angle_msg<<<AA / 32, 256, 0, stream>>>(
        xba, eib, Wang + (size_t)l * 32 * DD, bang + l * DD,
        Wrest + (size_t)l * 5 * DD, brest + l * DD, T, preB);
    // T (cur_h_ba) fully consumed above; GEMM1 may overwrite it
    k_gemm<false, true><<<(EE + 127) / 128, 256, 0, stream>>>(
        preB, W1_g + (size_t)l * DD * DD, b1_g + l * DD, T, nullptr, nullptr, sumA, sqA, EE);
    k_bn_finalize<<<1, 128, 0, stream>>>(sumA, sqA, bng_g + l * DD, bnb_g + l * DD, scA, shA, 1.f / EE);
    if (obn) {
      k_gemm<true, true><<<(EE + 127) / 128, 256, 0, stream>>>(
          T, W2_g + (size_t)l * DD * DD, b2_g + l * DD, hB_nxt, scA, shA, sumB, sqB, EE);
      k_bn_finalize<<<1, 128, 0, stream>>>(sumB, sqB, obng_b + l * DD, obnb_b + l * DD, scB, shB, 1.f / EE);
      k_bn_relu<<<ED / 256, 256, 0, stream>>>(hB_nxt, scB, shB);
    } else {
      k_gemm<true, false><<<(EE + 127) / 128, 256, 0, stream>>>(
          T, W2_g + (size_t)l * DD * DD, b2_g + l * DD, hB_nxt, scA, shA, nullptr, nullptr, EE);
    }

    hA_cur = hA_nxt;
    hB_cur = hB_nxt;
  }
}

// Round 2
// 7261.126 us; speedup vs baseline: 1.7899x; 1.7899x over previous
//
#include <hip/hip_runtime.h>
#include <cstdint>
#include <cstddef>

#define NN 100000
#define EE 200000
#define AA 400000
#define DD 128
#define LL 5

// RBF constants (module-level constants in the reference, not inputs)
__constant__ float c_bf_start[8] = {0.f, 0.f, 3.f, 0.f, 0.f, 0.f, 0.f, 0.f};
__constant__ float c_bf_step[8]  = {0.1f, 0.05f, 0.3f, 0.05f, 0.05f, 0.05f, 0.5f, 0.05f};
__constant__ int   c_bf_cnt[8]   = {20, 20, 30, 20, 20, 20, 20, 20};
__constant__ float c_bf_gam[8]   = {10.f, 1.f, 1.f, 1.f, 1.f, 1.f, 2.f, 1.f};

// ---------------- atom embedding: h[n,d] = sum_f atab[f, x[n,f], d] ----------------
__global__ __launch_bounds__(128) void k_atom_embed(
    const int* __restrict__ xa, const float* __restrict__ tab, float* __restrict__ h)
{
  __shared__ int idx[9];
  int n = blockIdx.x, d = threadIdx.x;
  if (d < 9) idx[d] = xa[n * 9 + d];
  __syncthreads();
  float s = 0.f;
#pragma unroll
  for (int f = 0; f < 9; ++f) s += tab[(f * 124 + idx[f]) * DD + d];
  h[(size_t)n * DD + d] = s;
}

// ---------------- bond embedding: int-embed + RBF(240) @ W + biases ----------------
__global__ __launch_bounds__(256) void k_bond_embed(
    const float* __restrict__ xf, const int* __restrict__ eai,
    const float* __restrict__ btab,   // [3,12,128] this layer
    const float* __restrict__ bfW,    // [240,128]  this layer
    const float* __restrict__ bfb,    // [8,128]    this layer
    float* __restrict__ out)          // [E,128]
{
  __shared__ float rbf[32][240];
  __shared__ float xfs[32][8];
  __shared__ int   ii[32][3];
  int tid = threadIdx.x;
  int e0 = blockIdx.x * 32;
  { int e = tid >> 3, f = tid & 7; xfs[e][f] = xf[(size_t)(e0 + e) * 8 + f]; }
  if (tid < 96) { int e = tid / 3, f = tid - 3 * e; ii[e][f] = eai[(size_t)(e0 + e) * 3 + f]; }
  __syncthreads();
#pragma unroll
  for (int i = 0; i < 30; ++i) {
    int j = tid + i * 256;
    int e = j / 240;
    int k = j - e * 240;
    int f = k / 30;
    int c = k - f * 30;
    float x = xfs[e][f];
    float cen = c_bf_start[f] + c_bf_step[f] * (float)c;
    float dx = x - cen;
    rbf[e][k] = (c < c_bf_cnt[f]) ? __expf(-c_bf_gam[f] * dx * dx) : 0.f;
  }
  __syncthreads();
  int cg = tid & 15, eg = tid >> 4;
  int c0 = cg * 8;
  int eb = eg * 2;
  float acc[2][8];
  {
    float bs[8] = {0, 0, 0, 0, 0, 0, 0, 0};
#pragma unroll
    for (int f = 0; f < 8; ++f) {
      float4 v0 = *(const float4*)&bfb[f * DD + c0];
      float4 v1 = *(const float4*)&bfb[f * DD + c0 + 4];
      bs[0] += v0.x; bs[1] += v0.y; bs[2] += v0.z; bs[3] += v0.w;
      bs[4] += v1.x; bs[5] += v1.y; bs[6] += v1.z; bs[7] += v1.w;
    }
#pragma unroll
    for (int e2 = 0; e2 < 2; ++e2) {
#pragma unroll
      for (int j = 0; j < 8; ++j) acc[e2][j] = bs[j];
#pragma unroll
      for (int f = 0; f < 3; ++f) {
        int row = f * 12 + ii[eb + e2][f];
        float4 v0 = *(const float4*)&btab[row * DD + c0];
        float4 v1 = *(const float4*)&btab[row * DD + c0 + 4];
        acc[e2][0] += v0.x; acc[e2][1] += v0.y; acc[e2][2] += v0.z; acc[e2][3] += v0.w;
        acc[e2][4] += v1.x; acc[e2][5] += v1.y; acc[e2][6] += v1.z; acc[e2][7] += v1.w;
      }
    }
  }
#pragma unroll 2
  for (int k = 0; k < 240; k += 4) {
    float4 w0[4], w1[4];
#pragma unroll
    for (int kk = 0; kk < 4; ++kk) {
      w0[kk] = *(const float4*)&bfW[(k + kk) * DD + c0];
      w1[kk] = *(const float4*)&bfW[(k + kk) * DD + c0 + 4];
    }
#pragma unroll
    for (int e2 = 0; e2 < 2; ++e2) {
      float4 r4 = *(const float4*)&rbf[eb + e2][k];
      float rr[4] = {r4.x, r4.y, r4.z, r4.w};
#pragma unroll
      for (int kk = 0; kk < 4; ++kk) {
        acc[e2][0] = fmaf(rr[kk], w0[kk].x, acc[e2][0]);
        acc[e2][1] = fmaf(rr[kk], w0[kk].y, acc[e2][1]);
        acc[e2][2] = fmaf(rr[kk], w0[kk].z, acc[e2][2]);
        acc[e2][3] = fmaf(rr[kk], w0[kk].w, acc[e2][3]);
        acc[e2][4] = fmaf(rr[kk], w1[kk].x, acc[e2][4]);
        acc[e2][5] = fmaf(rr[kk], w1[kk].y, acc[e2][5]);
        acc[e2][6] = fmaf(rr[kk], w1[kk].z, acc[e2][6]);
        acc[e2][7] = fmaf(rr[kk], w1[kk].w, acc[e2][7]);
      }
    }
  }
#pragma unroll
  for (int e2 = 0; e2 < 2; ++e2) {
    int e = e0 + eb + e2;
    *(float4*)&out[(size_t)e * DD + c0]     = make_float4(acc[e2][0], acc[e2][1], acc[e2][2], acc[e2][3]);
    *(float4*)&out[(size_t)e * DD + c0 + 4] = make_float4(acc[e2][4], acc[e2][5], acc[e2][6], acc[e2][7]);
  }
}

// ---------------- CSR build: count / scan / fill ----------------
__global__ __launch_bounds__(256) void k_count(
    const int* __restrict__ dst, int* __restrict__ counts, int M)
{
  int i = blockIdx.x * 256 + threadIdx.x;
  if (i < M) atomicAdd(&counts[dst[i]], 1);
}

// single-block exclusive scan (16 waves, shfl-based), n up to a few 100k
__global__ __launch_bounds__(1024) void k_scan(
    const int* __restrict__ counts, int* __restrict__ offs, int n, int total)
{
  __shared__ int wsum[16];
  int lane = threadIdx.x & 63, w = threadIdx.x >> 6;
  int carry = 0;
  for (int base = 0; base < n; base += 1024) {
    int i = base + threadIdx.x;
    int v = (i < n) ? counts[i] : 0;
    int s = v;
#pragma unroll
    for (int d = 1; d < 64; d <<= 1) { int t = __shfl_up(s, d); if (lane >= d) s += t; }
    if (lane == 63) wsum[w] = s;
    __syncthreads();
    int wexcl = 0;
    for (int j = 0; j < w; ++j) wexcl += wsum[j];
    int btot = wexcl;
    for (int j = w; j < 16; ++j) btot += wsum[j];
    if (i < n) offs[i] = carry + wexcl + (s - v);
    carry += btot;
    __syncthreads();
  }
  if (threadIdx.x == 0) offs[n] = total;
}

__global__ __launch_bounds__(256) void k_fill(
    const int* __restrict__ dst, int* __restrict__ cursor,
    int* __restrict__ perm, int M)
{
  int i = blockIdx.x * 256 + threadIdx.x;
  if (i < M) { int p = atomicAdd(&cursor[dst[i]], 1); perm[p] = i; }
}

// ---------------- atom gather: pre[n] = (1+eps)*h_eff[n] + sum relu(h_eff[src]+hB_eff[e])
// one wave per node; lazy outer-BN affine+relu applied on reads when AFF
template<bool AFF>
__global__ __launch_bounds__(256) void k_atom_gather(
    const int* __restrict__ offs, const int* __restrict__ perm,
    const int* __restrict__ ei,                 // src = ei[0..E)
    const float* __restrict__ h, const float* __restrict__ hB,
    const float* __restrict__ scH, const float* __restrict__ shH,
    const float* __restrict__ scB, const float* __restrict__ shB,
    const float* __restrict__ eps_l, float* __restrict__ pre)
{
  int w = blockIdx.x * 4 + (threadIdx.x >> 6);   // node id, grid exact
  int lane = threadIdx.x & 63;
  int c = lane * 2;
  float2 sH, tH, sB, tB;
  if (AFF) {
    sH = *(const float2*)&scH[c]; tH = *(const float2*)&shH[c];
    sB = *(const float2*)&scB[c]; tB = *(const float2*)&shB[c];
  }
  float ep = 1.f + *eps_l;
  float2 self = *(const float2*)&h[(size_t)w * DD + c];
  if (AFF) {
    self.x = fmaxf(fmaf(self.x, sH.x, tH.x), 0.f);
    self.y = fmaxf(fmaf(self.y, sH.y, tH.y), 0.f);
  }
  float ax = self.x * ep, ay = self.y * ep;
  int jb = offs[w], je = offs[w + 1];
  for (int j = jb; j < je; ++j) {
    int e = perm[j];
    int s = ei[e];
    float2 hv = *(const float2*)&h[(size_t)s * DD + c];
    float2 bv = *(const float2*)&hB[(size_t)e * DD + c];
    if (AFF) {
      hv.x = fmaxf(fmaf(hv.x, sH.x, tH.x), 0.f);
      hv.y = fmaxf(fmaf(hv.y, sH.y, tH.y), 0.f);
      bv.x = fmaxf(fmaf(bv.x, sB.x, tB.x), 0.f);
      bv.y = fmaxf(fmaf(bv.y, sB.y, tB.y), 0.f);
    }
    ax += fmaxf(hv.x + bv.x, 0.f);
    ay += fmaxf(hv.y + bv.y, 0.f);
  }
  *(float2*)&pre[(size_t)w * DD + c] = make_float2(ax, ay);
}

// ---------------- angle gather: pre[e] = (1+eps)*x[e] + sum relu(x[srcb]+angle_emb)
// one wave per dst edge; angle RBF embedding computed inline per angle
__global__ __launch_bounds__(256) void k_angle_gather(
    const int* __restrict__ offs, const int* __restrict__ perm,
    const int* __restrict__ eib,                // src = eib[0..A)
    const float* __restrict__ xba,
    const float* __restrict__ Wa, const float* __restrict__ ba,
    const float* __restrict__ Wr, const float* __restrict__ br,
    const float* __restrict__ x, const float* __restrict__ eps_l,
    float* __restrict__ pre)
{
  int w = blockIdx.x * 4 + (threadIdx.x >> 6);   // dst edge id, grid exact
  int lane = threadIdx.x & 63;
  int c = lane * 2;
  float2 bias;
  {
    float2 b1 = *(const float2*)&ba[c];
    float2 b2 = *(const float2*)&br[c];
    bias.x = b1.x + b2.x; bias.y = b1.y + b2.y;
  }
  float ep = 1.f + *eps_l;
  float2 self = *(const float2*)&x[(size_t)w * DD + c];
  float ax = self.x * ep, ay = self.y * ep;
  int jb = offs[w], je = offs[w + 1];
  for (int j = jb; j < je; ++j) {
    int a = perm[j];
    int s = eib[a];
    float x0 = xba[(size_t)a * 6];
    float e0 = bias.x, e1 = bias.y;
#pragma unroll
    for (int k = 0; k < 32; ++k) {
      float d = x0 - 0.1f * (float)k;
      float r = __expf(-10.f * d * d);
      float2 wv = *(const float2*)&Wa[k * DD + c];
      e0 = fmaf(r, wv.x, e0);
      e1 = fmaf(r, wv.y, e1);
    }
#pragma unroll
    for (int k = 0; k < 5; ++k) {
      float xr = xba[(size_t)a * 6 + 1 + k];
      float2 wv = *(const float2*)&Wr[k * DD + c];
      e0 = fmaf(xr, wv.x, e0);
      e1 = fmaf(xr, wv.y, e1);
    }
    float2 xs = *(const float2*)&x[(size_t)s * DD + c];
    ax += fmaxf(xs.x + e0, 0.f);
    ay += fmaxf(xs.y + e1, 0.f);
  }
  *(float2*)&pre[(size_t)w * DD + c] = make_float2(ax, ay);
}

// ---------------- BN finalize: scale/shift from sums ----------------
__global__ __launch_bounds__(128) void k_bn_finalize(
    const float* __restrict__ sum, const float* __restrict__ sq,
    const float* __restrict__ g, const float* __restrict__ be,
    float* __restrict__ scale, float* __restrict__ shift, float invM)
{
  int c = threadIdx.x;
  float mean = sum[c] * invM;
  float var = sq[c] * invM - mean * mean;
  float s = g[c] / sqrtf(var + 1e-5f);
  scale[c] = s;
  shift[c] = be[c] - mean * s;
}

// ---------------- GEMM [M,128]@[128,128]+bias, optional input-affine-relu, out stats
template<bool IN_AFFINE, bool OUT_STATS>
__global__ __launch_bounds__(256) void k_gemm(
    const float* __restrict__ A, const float* __restrict__ W,
    const float* __restrict__ bias, float* __restrict__ out,
    const float* __restrict__ iscale, const float* __restrict__ ishift,
    float* __restrict__ osum, float* __restrict__ osq, int M)
{
  __shared__ float As[128][33];
  __shared__ float Bs[32][128];
  __shared__ float redsum[128];
  __shared__ float redsq[128];
  int tid = threadIdx.x;
  int row0 = blockIdx.x * 128;
  int cg = tid & 15, rg = tid >> 4;
  int c0 = cg * 8, r0 = rg * 8;
  float acc[8][8];
#pragma unroll
  for (int i = 0; i < 8; ++i)
#pragma unroll
    for (int j = 0; j < 8; ++j) acc[i][j] = 0.f;

  for (int kc = 0; kc < 4; ++kc) {
    int k0 = kc * 32;
#pragma unroll
    for (int i = 0; i < 4; ++i) {
      int vid = tid + i * 256;
      int r = vid >> 3;
      int k4 = (vid & 7) * 4;
      int grow = row0 + r;
      float4 v = make_float4(0.f, 0.f, 0.f, 0.f);
      if (grow < M) v = *(const float4*)&A[(size_t)grow * DD + k0 + k4];
      if (IN_AFFINE) {
        float4 sc = *(const float4*)&iscale[k0 + k4];
        float4 sh = *(const float4*)&ishift[k0 + k4];
        v.x = fmaxf(fmaf(v.x, sc.x, sh.x), 0.f);
        v.y = fmaxf(fmaf(v.y, sc.y, sh.y), 0.f);
        v.z = fmaxf(fmaf(v.z, sc.z, sh.z), 0.f);
        v.w = fmaxf(fmaf(v.w, sc.w, sh.w), 0.f);
      }
      As[r][k4] = v.x; As[r][k4 + 1] = v.y; As[r][k4 + 2] = v.z; As[r][k4 + 3] = v.w;
    }
#pragma unroll
    for (int i = 0; i < 4; ++i) {
      int vid = tid + i * 256;
      int kl = vid >> 5;
      int c4 = (vid & 31) * 4;
      *(float4*)&Bs[kl][c4] = *(const float4*)&W[(size_t)(k0 + kl) * DD + c4];
    }
    __syncthreads();
#pragma unroll 4
    for (int kl = 0; kl < 32; ++kl) {
      float4 b0 = *(const float4*)&Bs[kl][c0];
      float4 b1 = *(const float4*)&Bs[kl][c0 + 4];
      float a[8];
#pragma unroll
      for (int i = 0; i < 8; ++i) a[i] = As[r0 + i][kl];
#pragma unroll
      for (int i = 0; i < 8; ++i) {
        acc[i][0] = fmaf(a[i], b0.x, acc[i][0]);
        acc[i][1] = fmaf(a[i], b0.y, acc[i][1]);
        acc[i][2] = fmaf(a[i], b0.z, acc[i][2]);
        acc[i][3] = fmaf(a[i], b0.w, acc[i][3]);
        acc[i][4] = fmaf(a[i], b1.x, acc[i][4]);
        acc[i][5] = fmaf(a[i], b1.y, acc[i][5]);
        acc[i][6] = fmaf(a[i], b1.z, acc[i][6]);
        acc[i][7] = fmaf(a[i], b1.w, acc[i][7]);
      }
    }
    __syncthreads();
  }
  if (OUT_STATS) {
    if (tid < 128) { redsum[tid] = 0.f; redsq[tid] = 0.f; }
    __syncthreads();
  }
  float4 bv0 = *(const float4*)&bias[c0];
  float4 bv1 = *(const float4*)&bias[c0 + 4];
  float csum[8], csq[8];
#pragma unroll
  for (int j = 0; j < 8; ++j) { csum[j] = 0.f; csq[j] = 0.f; }
#pragma unroll
  for (int i = 0; i < 8; ++i) {
    int grow = row0 + r0 + i;
    if (grow < M) {
      float o[8];
      o[0] = acc[i][0] + bv0.x; o[1] = acc[i][1] + bv0.y;
      o[2] = acc[i][2] + bv0.z; o[3] = acc[i][3] + bv0.w;
      o[4] = acc[i][4] + bv1.x; o[5] = acc[i][5] + bv1.y;
      o[6] = acc[i][6] + bv1.z; o[7] = acc[i][7] + bv1.w;
      *(float4*)&out[(size_t)grow * DD + c0]     = make_float4(o[0], o[1], o[2], o[3]);
      *(float4*)&out[(size_t)grow * DD + c0 + 4] = make_float4(o[4], o[5], o[6], o[7]);
      if (OUT_STATS) {
#pragma unroll
        for (int j = 0; j < 8; ++j) { csum[j] += o[j]; csq[j] += o[j] * o[j]; }
      }
    }
  }
  if (OUT_STATS) {
#pragma unroll
    for (int j = 0; j < 8; ++j) {
      atomicAdd(&redsum[c0 + j], csum[j]);
      atomicAdd(&redsq[c0 + j],  csq[j]);
    }
    __syncthreads();
    if (tid < 128) {
      atomicAdd(&osum[tid], redsum[tid]);
      atomicAdd(&osq[tid],  redsq[tid]);
    }
  }
}

extern "C" void kernel_launch(void* const* d_in, const int* in_sizes, int n_in,
                              void* d_out, int out_size, void* d_ws, size_t ws_size,
                              hipStream_t stream)
{
  (void)in_sizes; (void)n_in; (void)out_size; (void)ws_size;
  const int*   x_atom = (const int*)  d_in[0];
  const int*   ei     = (const int*)  d_in[1];
  const int*   eai    = (const int*)  d_in[2];
  const int*   eib    = (const int*)  d_in[3];
  const float* xf     = (const float*)d_in[4];
  const float* xba    = (const float*)d_in[5];
  const float* atab   = (const float*)d_in[6];
  const float* btab   = (const float*)d_in[7];
  const float* bfW    = (const float*)d_in[8];
  const float* bfb    = (const float*)d_in[9];
  const float* Wang   = (const float*)d_in[10];
  const float* bang   = (const float*)d_in[11];
  const float* Wrest  = (const float*)d_in[12];
  const float* brest  = (const float*)d_in[13];
  const float* eps_a  = (const float*)d_in[14];
  const float* W1_a   = (const float*)d_in[15];
  const float* b1_a   = (const float*)d_in[16];
  const float* bng_a  = (const float*)d_in[17];
  const float* bnb_a  = (const float*)d_in[18];
  const float* W2_a   = (const float*)d_in[19];
  const float* b2_a   = (const float*)d_in[20];
  const float* eps_g  = (const float*)d_in[21];
  const float* W1_g   = (const float*)d_in[22];
  const float* b1_g   = (const float*)d_in[23];
  const float* bng_g  = (const float*)d_in[24];
  const float* bnb_g  = (const float*)d_in[25];
  const float* W2_g   = (const float*)d_in[26];
  const float* b2_g   = (const float*)d_in[27];
  const float* obng_a = (const float*)d_in[28];
  const float* obnb_a = (const float*)d_in[29];
  const float* obng_b = (const float*)d_in[30];
  const float* obnb_b = (const float*)d_in[31];

  float* out_a = (float*)d_out;                 // final h [N,128]
  float* out_b = out_a + (size_t)NN * DD;       // final h_ba [E,128]
  float* ws = (float*)d_ws;
  const size_t ED = (size_t)EE * DD, ND = (size_t)NN * DD;
  // ws layout: preB | T | hB0 | hA0 | stats(1280 f) | CSR ints (~4.8 MB)
  float* preB  = ws;
  float* T     = ws + ED;
  float* hB0   = ws + 2 * ED;
  float* hA0   = ws + 3 * ED;
  float* stats = ws + 3 * ED + ND;
  float* sum1 = stats,        *sq1 = stats + 128;
  float* sum2 = stats + 256,  *sq2 = stats + 384;
  float* sc1  = stats + 512,  *sh1 = stats + 640;
  float* oscH = stats + 768,  *oshH = stats + 896;    // atom outer BN affine (lazy)
  float* oscB = stats + 1024, *oshB = stats + 1152;   // bond outer BN affine (lazy)
  int* offsA = (int*)(stats + 1280);   // [N+1]
  int* permA = offsA + NN + 1;         // [E]
  int* offsB = permA + EE;             // [E+1]
  int* permB = offsB + EE + 1;         // [A]
  int* curA  = permB + AA;             // [N] counts->cursor
  int* curB  = curA + NN;              // [E]

  // ---- CSR build (topology is launch-invariant; reused across all 5 layers) ----
  hipMemsetAsync(curA, 0, NN * sizeof(int), stream);
  hipMemsetAsync(curB, 0, EE * sizeof(int), stream);
  k_count<<<(EE + 255) / 256, 256, 0, stream>>>(ei + EE, curA, EE);
  k_count<<<(AA + 255) / 256, 256, 0, stream>>>(eib + AA, curB, AA);
  k_scan<<<1, 1024, 0, stream>>>(curA, offsA, NN, EE);
  k_scan<<<1, 1024, 0, stream>>>(curB, offsB, EE, AA);
  hipMemcpyAsync(curA, offsA, NN * sizeof(int), hipMemcpyDeviceToDevice, stream);
  hipMemcpyAsync(curB, offsB, EE * sizeof(int), hipMemcpyDeviceToDevice, stream);
  k_fill<<<(EE + 255) / 256, 256, 0, stream>>>(ei + EE, curA, permA, EE);
  k_fill<<<(AA + 255) / 256, 256, 0, stream>>>(eib + AA, curB, permB, AA);

  // ---- initial embeddings ----
  k_atom_embed<<<NN, 128, 0, stream>>>(x_atom, atab, hA0);
  k_bond_embed<<<EE / 32, 256, 0, stream>>>(xf, eai, btab, bfW, bfb, hB0);

  float* hA_cur = hA0;
  float* hB_cur = hB0;
  for (int l = 0; l < LL; ++l) {
    float* hA_nxt = (l & 1) ? hA0 : out_a;   // l=4 lands in d_out
    float* hB_nxt = (l & 1) ? hB0 : out_b;
    const bool obn = (l < LL - 1);

    // ---- atom GIN conv ----
    if (l == 0)
      k_atom_gather<false><<<NN / 4, 256, 0, stream>>>(
          offsA, permA, ei, hA_cur, hB_cur, nullptr, nullptr, nullptr, nullptr,
          eps_a + l, preB);
    else
      k_atom_gather<true><<<NN / 4, 256, 0, stream>>>(
          offsA, permA, ei, hA_cur, hB_cur, oscH, oshH, oscB, oshB,
          eps_a + l, preB);
    hipMemsetAsync(stats, 0, 512 * sizeof(float), stream);
    k_gemm<false, true><<<(NN + 127) / 128, 256, 0, stream>>>(
        preB, W1_a + (size_t)l * DD * DD, b1_a + l * DD, T, nullptr, nullptr, sum1, sq1, NN);
    k_bn_finalize<<<1, 128, 0, stream>>>(sum1, sq1, bng_a + l * DD, bnb_a + l * DD, sc1, sh1, 1.f / NN);
    if (obn) {
      k_gemm<true, true><<<(NN + 127) / 128, 256, 0, stream>>>(
          T, W2_a + (size_t)l * DD * DD, b2_a + l * DD, hA_nxt, sc1, sh1, sum2, sq2, NN);
      k_bn_finalize<<<1, 128, 0, stream>>>(sum2, sq2, obng_a + l * DD, obnb_a + l * DD, oscH, oshH, 1.f / NN);
    } else {
      k_gemm<true, false><<<(NN + 127) / 128, 256, 0, stream>>>(
          T, W2_a + (size_t)l * DD * DD, b2_a + l * DD, hA_nxt, sc1, sh1, nullptr, nullptr, NN);
    }

    // ---- bond GIN conv ----
    k_bond_embed<<<EE / 32, 256, 0, stream>>>(
        xf, eai, btab + (size_t)(l + 1) * 3 * 12 * DD,
        bfW + (size_t)(l + 1) * 240 * DD, bfb + (size_t)(l + 1) * 8 * DD, T);
    k_angle_gather<<<EE / 4, 256, 0, stream>>>(
        offsB, permB, eib, xba,
        Wang + (size_t)l * 32 * DD, bang + l * DD,
        Wrest + (size_t)l * 5 * DD, brest + l * DD, T, eps_g + l, preB);
    hipMemsetAsync(stats, 0, 512 * sizeof(float), stream);
    // T (cur_h_ba) fully consumed by gather; GEMM1 may overwrite it
    k_gemm<false, true><<<(EE + 127) / 128, 256, 0, stream>>>(
        preB, W1_g + (size_t)l * DD * DD, b1_g + l * DD, T, nullptr, nullptr, sum1, sq1, EE);
    k_bn_finalize<<<1, 128, 0, stream>>>(sum1, sq1, bng_g + l * DD, bnb_g + l * DD, sc1, sh1, 1.f / EE);
    if (obn) {
      k_gemm<true, true><<<(EE + 127) / 128, 256, 0, stream>>>(
          T, W2_g + (size_t)l * DD * DD, b2_g + l * DD, hB_nxt, sc1, sh1, sum2, sq2, EE);
      k_bn_finalize<<<1, 128, 0, stream>>>(sum2, sq2, obng_b + l * DD, obnb_b + l * DD, oscB, oshB, 1.f / EE);
    } else {
      k_gemm<true, false><<<(EE + 127) / 128, 256, 0, stream>>>(
          T, W2_g + (size_t)l * DD * DD, b2_g + l * DD, hB_nxt, sc1, sh1, nullptr, nullptr, EE);
    }

    hA_cur = hA_nxt;
    hB_cur = hB_nxt;
  }
}

// Round 5
// 5722.203 us; speedup vs baseline: 2.2712x; 1.2689x over previous
//
#include <hip/hip_runtime.h>
#include <cstdint>
#include <cstddef>

#define NN 100000
#define EE 200000
#define AA 400000
#define DD 128
#define LL 5

typedef __attribute__((ext_vector_type(8))) short short8v;   // 8 bf16 (4 VGPRs)
typedef __attribute__((ext_vector_type(4))) float f4v;       // MFMA acc

__constant__ float c_bf_start[8] = {0.f, 0.f, 3.f, 0.f, 0.f, 0.f, 0.f, 0.f};
__constant__ float c_bf_step[8]  = {0.1f, 0.05f, 0.3f, 0.05f, 0.05f, 0.05f, 0.5f, 0.05f};
__constant__ int   c_bf_cnt[8]   = {20, 20, 30, 20, 20, 20, 20, 20};
__constant__ float c_bf_gam[8]   = {10.f, 1.f, 1.f, 1.f, 1.f, 1.f, 2.f, 1.f};

__device__ inline short f2bf(float v) {
  unsigned u = __float_as_uint(v);
  unsigned r = (u + 0x7fffu + ((u >> 16) & 1u)) >> 16;   // RNE
  return (short)r;
}
__device__ inline float bf2f(short h) { return __uint_as_float(((unsigned)(unsigned short)h) << 16); }
// 3-way split: v = s0 + s1 + s2 + O(2^-27 |v|)
__device__ inline void split3(float v, short& s0, short& s1, short& s2) {
  s0 = f2bf(v);
  float r1 = v - bf2f(s0);
  s1 = f2bf(r1);
  float r2 = r1 - bf2f(s1);
  s2 = f2bf(r2);
}

// ---------------- atom embedding ----------------
__global__ __launch_bounds__(128) void k_atom_embed(
    const int* __restrict__ xa, const float* __restrict__ tab, float* __restrict__ h)
{
  __shared__ int idx[9];
  int n = blockIdx.x, d = threadIdx.x;
  if (d < 9) idx[d] = xa[n * 9 + d];
  __syncthreads();
  float s = 0.f;
#pragma unroll
  for (int f = 0; f < 9; ++f) s += tab[(f * 124 + idx[f]) * DD + d];
  h[(size_t)n * DD + d] = s;
}

// ---------------- prep: W[k][n] -> Wt planes [n][k] bf16 x3 (5 mats per call) ----
__global__ __launch_bounds__(128) void k_prep_w(
    const float* __restrict__ src,
    short* __restrict__ d0, short* __restrict__ d1, short* __restrict__ d2)
{
  int b = blockIdx.x;            // 5*128
  int l = b >> 7, n = b & 127;
  int k = threadIdx.x;
  float v = src[l * 16384 + k * 128 + n];
  short s0, s1, s2; split3(v, s0, s1, s2);
  d0[l * 16384 + n * 128 + k] = s0;
  d1[l * 16384 + n * 128 + k] = s1;
  d2[l * 16384 + n * 128 + k] = s2;
}

// ---------------- prep: bond B matrix [6][n=128][k=320] bf16 x3 --------------
// k layout: f*32+c (f<8, RBF) | 256+j one-hot f0/f1 | 288+j one-hot f2, 300: const-1
__global__ __launch_bounds__(320) void k_prep_bond(
    const float* __restrict__ bfW,    // [6][8][30][128]
    const float* __restrict__ btab,   // [6][3][12][128]
    const float* __restrict__ bfb,    // [6][8][128]
    short* __restrict__ d0, short* __restrict__ d1, short* __restrict__ d2)
{
  int b = blockIdx.x;            // 6*128
  int l = b >> 7, n = b & 127;
  int k = threadIdx.x;           // 0..319
  float v = 0.f;
  if (k < 256) {
    int f = k >> 5, c = k & 31;
    if (c < 30) v = bfW[(((size_t)l * 8 + f) * 30 + c) * 128 + n];
  } else if (k < 288) {
    int j = k - 256;
    if (j < 12)       v = btab[(((size_t)l * 3 + 0) * 12 + j) * 128 + n];
    else if (j < 24)  v = btab[(((size_t)l * 3 + 1) * 12 + (j - 12)) * 128 + n];
  } else {
    int j = k - 288;
    if (j < 12)       v = btab[(((size_t)l * 3 + 2) * 12 + j) * 128 + n];
    else if (j == 12) {
      for (int f = 0; f < 8; ++f) v += bfb[((size_t)l * 8 + f) * 128 + n];
    }
  }
  short s0, s1, s2; split3(v, s0, s1, s2);
  d0[(size_t)l * 40960 + n * 320 + k] = s0;
  d1[(size_t)l * 40960 + n * 320 + k] = s1;
  d2[(size_t)l * 40960 + n * 320 + k] = s2;
}

// ---------------- CSR build ----------------
__global__ __launch_bounds__(256) void k_count(
    const int* __restrict__ dst, int* __restrict__ counts, int M)
{
  int i = blockIdx.x * 256 + threadIdx.x;
  if (i < M) atomicAdd(&counts[dst[i]], 1);
}

__global__ __launch_bounds__(1024) void k_scan(
    const int* __restrict__ counts, int* __restrict__ offs, int n, int total)
{
  __shared__ int wsum[16];
  int lane = threadIdx.x & 63, w = threadIdx.x >> 6;
  int carry = 0;
  for (int base = 0; base < n; base += 1024) {
    int i = base + threadIdx.x;
    int v = (i < n) ? counts[i] : 0;
    int s = v;
#pragma unroll
    for (int d = 1; d < 64; d <<= 1) { int t = __shfl_up(s, d); if (lane >= d) s += t; }
    if (lane == 63) wsum[w] = s;
    __syncthreads();
    int wexcl = 0;
    for (int j = 0; j < w; ++j) wexcl += wsum[j];
    int btot = wexcl;
    for (int j = w; j < 16; ++j) btot += wsum[j];
    if (i < n) offs[i] = carry + wexcl + (s - v);
    carry += btot;
    __syncthreads();
  }
  if (threadIdx.x == 0) offs[n] = total;
}

__global__ __launch_bounds__(256) void k_fill(
    const int* __restrict__ dst, int* __restrict__ cursor,
    int* __restrict__ perm, int M)
{
  int i = blockIdx.x * 256 + threadIdx.x;
  if (i < M) { int p = atomicAdd(&cursor[dst[i]], 1); perm[p] = i; }
}

// ---------------- atom gather -> pre (fp32) ----------------
template<bool AFF>
__global__ __launch_bounds__(256) void k_atom_gather(
    const int* __restrict__ offs, const int* __restrict__ perm,
    const int* __restrict__ ei,
    const float* __restrict__ h, const float* __restrict__ hB,
    const float* __restrict__ scH, const float* __restrict__ shH,
    const float* __restrict__ scB, const float* __restrict__ shB,
    const float* __restrict__ eps_l, float* __restrict__ pre)
{
  int w = blockIdx.x * 4 + (threadIdx.x >> 6);
  int lane = threadIdx.x & 63;
  int c = lane * 2;
  float2 sH, tH, sB, tB;
  if (AFF) {
    sH = *(const float2*)&scH[c]; tH = *(const float2*)&shH[c];
    sB = *(const float2*)&scB[c]; tB = *(const float2*)&shB[c];
  }
  float ep = 1.f + *eps_l;
  float2 self = *(const float2*)&h[(size_t)w * DD + c];
  if (AFF) {
    self.x = fmaxf(fmaf(self.x, sH.x, tH.x), 0.f);
    self.y = fmaxf(fmaf(self.y, sH.y, tH.y), 0.f);
  }
  float ax = self.x * ep, ay = self.y * ep;
  int jb = offs[w], je = offs[w + 1];
  for (int j = jb; j < je; ++j) {
    int e = perm[j];
    int s = ei[e];
    float2 hv = *(const float2*)&h[(size_t)s * DD + c];
    float2 bv = *(const float2*)&hB[(size_t)e * DD + c];
    if (AFF) {
      hv.x = fmaxf(fmaf(hv.x, sH.x, tH.x), 0.f);
      hv.y = fmaxf(fmaf(hv.y, sH.y, tH.y), 0.f);
      bv.x = fmaxf(fmaf(bv.x, sB.x, tB.x), 0.f);
      bv.y = fmaxf(fmaf(bv.y, sB.y, tB.y), 0.f);
    }
    ax += fmaxf(hv.x + bv.x, 0.f);
    ay += fmaxf(hv.y + bv.y, 0.f);
  }
  *(float2*)&pre[(size_t)w * DD + c] = make_float2(ax, ay);
}

// ---------------- angle gather -> pre (fp32) ----------------
__global__ __launch_bounds__(256) void k_angle_gather(
    const int* __restrict__ offs, const int* __restrict__ perm,
    const int* __restrict__ eib, const float* __restrict__ xba,
    const float* __restrict__ Wa, const float* __restrict__ ba,
    const float* __restrict__ Wr, const float* __restrict__ br,
    const float* __restrict__ x, const float* __restrict__ eps_l,
    float* __restrict__ pre)
{
  int w = blockIdx.x * 4 + (threadIdx.x >> 6);
  int lane = threadIdx.x & 63;
  int c = lane * 2;
  float2 bias;
  {
    float2 b1 = *(const float2*)&ba[c];
    float2 b2 = *(const float2*)&br[c];
    bias.x = b1.x + b2.x; bias.y = b1.y + b2.y;
  }
  float ep = 1.f + *eps_l;
  float2 self = *(const float2*)&x[(size_t)w * DD + c];
  float ax = self.x * ep, ay = self.y * ep;
  int jb = offs[w], je = offs[w + 1];
  for (int j = jb; j < je; ++j) {
    int a = perm[j];
    int s = eib[a];
    float x0 = xba[(size_t)a * 6];
    float e0 = bias.x, e1 = bias.y;
#pragma unroll
    for (int k = 0; k < 32; ++k) {
      float d = x0 - 0.1f * (float)k;
      float r = __expf(-10.f * d * d);
      float2 wv = *(const float2*)&Wa[k * DD + c];
      e0 = fmaf(r, wv.x, e0);
      e1 = fmaf(r, wv.y, e1);
    }
#pragma unroll
    for (int k = 0; k < 5; ++k) {
      float xr = xba[(size_t)a * 6 + 1 + k];
      float2 wv = *(const float2*)&Wr[k * DD + c];
      e0 = fmaf(xr, wv.x, e0);
      e1 = fmaf(xr, wv.y, e1);
    }
    float2 xs = *(const float2*)&x[(size_t)s * DD + c];
    ax += fmaxf(xs.x + e0, 0.f);
    ay += fmaxf(xs.y + e1, 0.f);
  }
  *(float2*)&pre[(size_t)w * DD + c] = make_float2(ax, ay);
}

// ---------------- BN finalize ----------------
__global__ __launch_bounds__(128) void k_bn_finalize(
    const float* __restrict__ sum, const float* __restrict__ sq,
    const float* __restrict__ g, const float* __restrict__ be,
    float* __restrict__ scale, float* __restrict__ shift, float invM)
{
  int c = threadIdx.x;
  float mean = sum[c] * invM;
  float var = sq[c] * invM - mean * mean;
  float s = g[c] / sqrtf(var + 1e-5f);
  scale[c] = s;
  shift[c] = be[c] - mean * s;
}

// ---------------- MFMA bf16x6 GEMM [M,128]@[128,128]+bias ----------------
// A fp32 (optional affine+relu), split 3-way in staging; B pre-split 3 planes.
template<bool AFF, bool OUT_STATS>
__global__ __launch_bounds__(256) void k_gemm_mfma(
    const float* __restrict__ Af,
    const short* __restrict__ Bt0, const short* __restrict__ Bt1,
    const short* __restrict__ Bt2,
    const float* __restrict__ bias, float* __restrict__ out,
    const float* __restrict__ iscale, const float* __restrict__ ishift,
    float* __restrict__ osum, float* __restrict__ osq, int M)
{
  __shared__ short As0[128][40], As1[128][40], As2[128][40];
  __shared__ short Bs0[128][40], Bs1[128][40], Bs2[128][40];
  __shared__ float redsum[128], redsq[128];
  int tid = threadIdx.x;
  int row0 = blockIdx.x * 128;
  int lane = tid & 63, wv = tid >> 6;
  int wr = (wv >> 1) * 64, wc = (wv & 1) * 64;
  int l15 = lane & 15, l4 = lane >> 4;

  if (OUT_STATS && tid < 128) { redsum[tid] = 0.f; redsq[tid] = 0.f; }

  f4v acc[4][4];
#pragma unroll
  for (int i = 0; i < 4; ++i)
#pragma unroll
    for (int j = 0; j < 4; ++j) acc[i][j] = (f4v){0.f, 0.f, 0.f, 0.f};

  for (int kc = 0; kc < 4; ++kc) {
    // stage B (3 planes)
#pragma unroll
    for (int i = 0; i < 2; ++i) {
      int vid = tid + i * 256;
      int n = vid >> 2, o = vid & 3;
      *(short8v*)&Bs0[n][o * 8] = *(const short8v*)&Bt0[n * 128 + kc * 32 + o * 8];
      *(short8v*)&Bs1[n][o * 8] = *(const short8v*)&Bt1[n * 128 + kc * 32 + o * 8];
      *(short8v*)&Bs2[n][o * 8] = *(const short8v*)&Bt2[n * 128 + kc * 32 + o * 8];
    }
    // stage A: fp32 load (+affine+relu), split3
#pragma unroll
    for (int i = 0; i < 4; ++i) {
      int vid = tid + i * 256;
      int r = vid >> 3, q = vid & 7;
      int grow = row0 + r;
      float4 v = make_float4(0.f, 0.f, 0.f, 0.f);
      if (grow < M) {
        v = *(const float4*)&Af[(size_t)grow * 128 + kc * 32 + q * 4];
        if (AFF) {
          float4 sc = *(const float4*)&iscale[kc * 32 + q * 4];
          float4 sh = *(const float4*)&ishift[kc * 32 + q * 4];
          v.x = fmaxf(fmaf(v.x, sc.x, sh.x), 0.f);
          v.y = fmaxf(fmaf(v.y, sc.y, sh.y), 0.f);
          v.z = fmaxf(fmaf(v.z, sc.z, sh.z), 0.f);
          v.w = fmaxf(fmaf(v.w, sc.w, sh.w), 0.f);
        }
      }
      short a0[4], a1[4], a2[4];
      split3(v.x, a0[0], a1[0], a2[0]);
      split3(v.y, a0[1], a1[1], a2[1]);
      split3(v.z, a0[2], a1[2], a2[2]);
      split3(v.w, a0[3], a1[3], a2[3]);
      *(short4*)&As0[r][q * 4] = make_short4(a0[0], a0[1], a0[2], a0[3]);
      *(short4*)&As1[r][q * 4] = make_short4(a1[0], a1[1], a1[2], a1[3]);
      *(short4*)&As2[r][q * 4] = make_short4(a2[0], a2[1], a2[2], a2[3]);
    }
    __syncthreads();

    short8v fa0[4], fa1[4], fb0[4], fb1[4], ft[4];
#pragma unroll
    for (int mt = 0; mt < 4; ++mt) fa0[mt] = *(const short8v*)&As0[wr + mt * 16 + l15][l4 * 8];
#pragma unroll
    for (int nt = 0; nt < 4; ++nt) fb0[nt] = *(const short8v*)&Bs0[wc + nt * 16 + l15][l4 * 8];
#pragma unroll
    for (int mt = 0; mt < 4; ++mt)
#pragma unroll
      for (int nt = 0; nt < 4; ++nt)
        acc[mt][nt] = __builtin_amdgcn_mfma_f32_16x16x32_bf16(fa0[mt], fb0[nt], acc[mt][nt], 0, 0, 0);
#pragma unroll
    for (int nt = 0; nt < 4; ++nt) fb1[nt] = *(const short8v*)&Bs1[wc + nt * 16 + l15][l4 * 8];
#pragma unroll
    for (int mt = 0; mt < 4; ++mt)
#pragma unroll
      for (int nt = 0; nt < 4; ++nt)
        acc[mt][nt] = __builtin_amdgcn_mfma_f32_16x16x32_bf16(fa0[mt], fb1[nt], acc[mt][nt], 0, 0, 0);
#pragma unroll
    for (int mt = 0; mt < 4; ++mt) fa1[mt] = *(const short8v*)&As1[wr + mt * 16 + l15][l4 * 8];
#pragma unroll
    for (int mt = 0; mt < 4; ++mt)
#pragma unroll
      for (int nt = 0; nt < 4; ++nt)
        acc[mt][nt] = __builtin_amdgcn_mfma_f32_16x16x32_bf16(fa1[mt], fb0[nt], acc[mt][nt], 0, 0, 0);
#pragma unroll
    for (int mt = 0; mt < 4; ++mt)
#pragma unroll
      for (int nt = 0; nt < 4; ++nt)
        acc[mt][nt] = __builtin_amdgcn_mfma_f32_16x16x32_bf16(fa1[mt], fb1[nt], acc[mt][nt], 0, 0, 0);
#pragma unroll
    for (int nt = 0; nt < 4; ++nt) ft[nt] = *(const short8v*)&Bs2[wc + nt * 16 + l15][l4 * 8];
#pragma unroll
    for (int mt = 0; mt < 4; ++mt)
#pragma unroll
      for (int nt = 0; nt < 4; ++nt)
        acc[mt][nt] = __builtin_amdgcn_mfma_f32_16x16x32_bf16(fa0[mt], ft[nt], acc[mt][nt], 0, 0, 0);
#pragma unroll
    for (int mt = 0; mt < 4; ++mt) ft[mt] = *(const short8v*)&As2[wr + mt * 16 + l15][l4 * 8];
#pragma unroll
    for (int mt = 0; mt < 4; ++mt)
#pragma unroll
      for (int nt = 0; nt < 4; ++nt)
        acc[mt][nt] = __builtin_amdgcn_mfma_f32_16x16x32_bf16(ft[mt], fb0[nt], acc[mt][nt], 0, 0, 0);
    __syncthreads();
  }

  // epilogue
  float cs[4], cq[4];
#pragma unroll
  for (int nt = 0; nt < 4; ++nt) { cs[nt] = 0.f; cq[nt] = 0.f; }
#pragma unroll
  for (int nt = 0; nt < 4; ++nt) {
    int col = wc + nt * 16 + l15;
    float bv = bias[col];
#pragma unroll
    for (int mt = 0; mt < 4; ++mt) {
#pragma unroll
      for (int j = 0; j < 4; ++j) {
        int gr = row0 + wr + mt * 16 + l4 * 4 + j;
        if (gr < M) {
          float o = acc[mt][nt][j] + bv;
          out[(size_t)gr * 128 + col] = o;
          if (OUT_STATS) { cs[nt] += o; cq[nt] += o * o; }
        }
      }
    }
  }
  if (OUT_STATS) {
#pragma unroll
    for (int nt = 0; nt < 4; ++nt) {
      int col = wc + nt * 16 + l15;
      atomicAdd(&redsum[col], cs[nt]);
      atomicAdd(&redsq[col],  cq[nt]);
    }
    __syncthreads();
    if (tid < 128) {
      atomicAdd(&osum[tid], redsum[tid]);
      atomicAdd(&osq[tid],  redsq[tid]);
    }
  }
}

// ---------------- bond embed as MFMA bf16x6 GEMM [E,320]@[320,128] ----------------
__global__ __launch_bounds__(256) void k_bond_mfma(
    const float* __restrict__ xf, const int* __restrict__ eai,
    const short* __restrict__ Bt0, const short* __restrict__ Bt1,
    const short* __restrict__ Bt2,
    float* __restrict__ out)
{
  __shared__ short As0[128][40], As1[128][40], As2[128][40];
  __shared__ short Bs0[128][40], Bs1[128][40], Bs2[128][40];
  __shared__ float xfs[128][8];
  __shared__ int   iis[128][3];
  int tid = threadIdx.x;
  int e0 = blockIdx.x * 128;
  int lane = tid & 63, wv = tid >> 6;
  int wr = (wv >> 1) * 64, wc = (wv & 1) * 64;
  int l15 = lane & 15, l4 = lane >> 4;

  // stage xf: 128 edges x 8 floats = 256 float4 chunks -> exactly one pass of 256 threads.
  // (R3/R4 BUG: a second pass wrote xfs[128..255] -> 2.5KB past the LDS allocation,
  //  corrupting the co-resident block's tiles. Single pass fixes it.)
  {
    int e = tid >> 1, f4i = (tid & 1) * 4;
    float4 v = make_float4(1e15f, 1e15f, 1e15f, 1e15f);
    if (e0 + e < EE) v = *(const float4*)&xf[(size_t)(e0 + e) * 8 + f4i];
    xfs[e][f4i] = v.x; xfs[e][f4i + 1] = v.y; xfs[e][f4i + 2] = v.z; xfs[e][f4i + 3] = v.w;
  }
  if (tid < 128) {
    int e = tid;
    if (e0 + e < EE) {
      iis[e][0] = eai[(size_t)(e0 + e) * 3];
      iis[e][1] = eai[(size_t)(e0 + e) * 3 + 1];
      iis[e][2] = eai[(size_t)(e0 + e) * 3 + 2];
    } else { iis[e][0] = -1; iis[e][1] = -1; iis[e][2] = -1; }
  }
  __syncthreads();

  f4v acc[4][4];
#pragma unroll
  for (int i = 0; i < 4; ++i)
#pragma unroll
    for (int j = 0; j < 4; ++j) acc[i][j] = (f4v){0.f, 0.f, 0.f, 0.f};

  for (int kc = 0; kc < 10; ++kc) {
#pragma unroll
    for (int i = 0; i < 2; ++i) {
      int vid = tid + i * 256;
      int n = vid >> 2, o = vid & 3;
      *(short8v*)&Bs0[n][o * 8] = *(const short8v*)&Bt0[n * 320 + kc * 32 + o * 8];
      *(short8v*)&Bs1[n][o * 8] = *(const short8v*)&Bt1[n * 320 + kc * 32 + o * 8];
      *(short8v*)&Bs2[n][o * 8] = *(const short8v*)&Bt2[n * 320 + kc * 32 + o * 8];
    }
    // build A chunk
#pragma unroll
    for (int i = 0; i < 2; ++i) {
      int vid = tid + i * 256;
      int e = vid >> 2, o = vid & 3;
      int ts = o * 8;
      float vals[8];
      if (kc < 8) {
        float x = xfs[e][kc];
        float gam = c_bf_gam[kc], st = c_bf_start[kc], sp = c_bf_step[kc];
        int cnt = c_bf_cnt[kc];
#pragma unroll
        for (int j = 0; j < 8; ++j) {
          int t = ts + j;
          float dx = x - (st + sp * (float)t);
          vals[j] = (t < cnt) ? __expf(-gam * dx * dx) : 0.f;
        }
      } else if (kc == 8) {
        int i0 = iis[e][0], i1 = iis[e][1];
#pragma unroll
        for (int j = 0; j < 8; ++j) {
          int t = ts + j;
          vals[j] = (t < 12) ? (t == i0 ? 1.f : 0.f)
                  : (t < 24) ? ((t - 12) == i1 ? 1.f : 0.f) : 0.f;
        }
      } else {
        int i2 = iis[e][2];
#pragma unroll
        for (int j = 0; j < 8; ++j) {
          int t = ts + j;
          vals[j] = (t < 12) ? (t == i2 ? 1.f : 0.f) : (t == 12 ? 1.f : 0.f);
        }
      }
      short a0[8], a1[8], a2[8];
#pragma unroll
      for (int j = 0; j < 8; ++j) split3(vals[j], a0[j], a1[j], a2[j]);
      short8v v0 = {a0[0], a0[1], a0[2], a0[3], a0[4], a0[5], a0[6], a0[7]};
      short8v v1 = {a1[0], a1[1], a1[2], a1[3], a1[4], a1[5], a1[6], a1[7]};
      short8v v2 = {a2[0], a2[1], a2[2], a2[3], a2[4], a2[5], a2[6], a2[7]};
      *(short8v*)&As0[e][ts] = v0;
      *(short8v*)&As1[e][ts] = v1;
      *(short8v*)&As2[e][ts] = v2;
    }
    __syncthreads();

    short8v fa0[4], fa1[4], fb0[4], fb1[4], ft[4];
#pragma unroll
    for (int mt = 0; mt < 4; ++mt) fa0[mt] = *(const short8v*)&As0[wr + mt * 16 + l15][l4 * 8];
#pragma unroll
    for (int nt = 0; nt < 4; ++nt) fb0[nt] = *(const short8v*)&Bs0[wc + nt * 16 + l15][l4 * 8];
#pragma unroll
    for (int mt = 0; mt < 4; ++mt)
#pragma unroll
      for (int nt = 0; nt < 4; ++nt)
        acc[mt][nt] = __builtin_amdgcn_mfma_f32_16x16x32_bf16(fa0[mt], fb0[nt], acc[mt][nt], 0, 0, 0);
#pragma unroll
    for (int nt = 0; nt < 4; ++nt) fb1[nt] = *(const short8v*)&Bs1[wc + nt * 16 + l15][l4 * 8];
#pragma unroll
    for (int mt = 0; mt < 4; ++mt)
#pragma unroll
      for (int nt = 0; nt < 4; ++nt)
        acc[mt][nt] = __builtin_amdgcn_mfma_f32_16x16x32_bf16(fa0[mt], fb1[nt], acc[mt][nt], 0, 0, 0);
#pragma unroll
    for (int nt = 0; nt < 4; ++nt) ft[nt] = *(const short8v*)&Bs2[wc + nt * 16 + l15][l4 * 8];
#pragma unroll
    for (int mt = 0; mt < 4; ++mt)
#pragma unroll
      for (int nt = 0; nt < 4; ++nt)
        acc[mt][nt] = __builtin_amdgcn_mfma_f32_16x16x32_bf16(fa0[mt], ft[nt], acc[mt][nt], 0, 0, 0);
    if (kc < 8) {   // A-lo planes are zero for one-hot/const chunks
#pragma unroll
      for (int mt = 0; mt < 4; ++mt) fa1[mt] = *(const short8v*)&As1[wr + mt * 16 + l15][l4 * 8];
#pragma unroll
      for (int mt = 0; mt < 4; ++mt)
#pragma unroll
        for (int nt = 0; nt < 4; ++nt)
          acc[mt][nt] = __builtin_amdgcn_mfma_f32_16x16x32_bf16(fa1[mt], fb0[nt], acc[mt][nt], 0, 0, 0);
#pragma unroll
      for (int mt = 0; mt < 4; ++mt)
#pragma unroll
        for (int nt = 0; nt < 4; ++nt)
          acc[mt][nt] = __builtin_amdgcn_mfma_f32_16x16x32_bf16(fa1[mt], fb1[nt], acc[mt][nt], 0, 0, 0);
#pragma unroll
      for (int mt = 0; mt < 4; ++mt) ft[mt] = *(const short8v*)&As2[wr + mt * 16 + l15][l4 * 8];
#pragma unroll
      for (int mt = 0; mt < 4; ++mt)
#pragma unroll
        for (int nt = 0; nt < 4; ++nt)
          acc[mt][nt] = __builtin_amdgcn_mfma_f32_16x16x32_bf16(ft[mt], fb0[nt], acc[mt][nt], 0, 0, 0);
    }
    __syncthreads();
  }

#pragma unroll
  for (int nt = 0; nt < 4; ++nt) {
    int col = wc + nt * 16 + l15;
#pragma unroll
    for (int mt = 0; mt < 4; ++mt) {
#pragma unroll
      for (int j = 0; j < 4; ++j) {
        int ge = e0 + wr + mt * 16 + l4 * 4 + j;
        if (ge < EE) out[(size_t)ge * 128 + col] = acc[mt][nt][j];
      }
    }
  }
}

extern "C" void kernel_launch(void* const* d_in, const int* in_sizes, int n_in,
                              void* d_out, int out_size, void* d_ws, size_t ws_size,
                              hipStream_t stream)
{
  (void)in_sizes; (void)n_in; (void)out_size; (void)ws_size;
  const int*   x_atom = (const int*)  d_in[0];
  const int*   ei     = (const int*)  d_in[1];
  const int*   eai    = (const int*)  d_in[2];
  const int*   eib    = (const int*)  d_in[3];
  const float* xf     = (const float*)d_in[4];
  const float* xba    = (const float*)d_in[5];
  const float* atab   = (const float*)d_in[6];
  const float* btab   = (const float*)d_in[7];
  const float* bfW    = (const float*)d_in[8];
  const float* bfb    = (const float*)d_in[9];
  const float* Wang   = (const float*)d_in[10];
  const float* bang   = (const float*)d_in[11];
  const float* Wrest  = (const float*)d_in[12];
  const float* brest  = (const float*)d_in[13];
  const float* eps_a  = (const float*)d_in[14];
  const float* W1_a   = (const float*)d_in[15];
  const float* b1_a   = (const float*)d_in[16];
  const float* bng_a  = (const float*)d_in[17];
  const float* bnb_a  = (const float*)d_in[18];
  const float* W2_a   = (const float*)d_in[19];
  const float* b2_a   = (const float*)d_in[20];
  const float* eps_g  = (const float*)d_in[21];
  const float* W1_g   = (const float*)d_in[22];
  const float* b1_g   = (const float*)d_in[23];
  const float* bng_g  = (const float*)d_in[24];
  const float* bnb_g  = (const float*)d_in[25];
  const float* W2_g   = (const float*)d_in[26];
  const float* b2_g   = (const float*)d_in[27];
  const float* obng_a = (const float*)d_in[28];
  const float* obnb_a = (const float*)d_in[29];
  const float* obng_b = (const float*)d_in[30];
  const float* obnb_b = (const float*)d_in[31];

  float* out_a = (float*)d_out;
  float* out_b = out_a + (size_t)NN * DD;
  char* base = (char*)d_ws;
  const size_t ED = (size_t)EE * DD, ND = (size_t)NN * DD;

  float* preB  = (float*)base;                 base += ED * 4;          // 102.4 MB
  float* T     = (float*)base;                 base += ED * 4;          // 102.4 MB
  float* hB0   = (float*)base;                 base += ED * 4;          // 102.4 MB
  float* hA0   = (float*)base;                 base += ND * 4;          // 51.2 MB
  float* stats = (float*)base;                 base += 1280 * 4;
  float* sum1 = stats,        *sq1 = stats + 128;
  float* sum2 = stats + 256,  *sq2 = stats + 384;
  float* sc1  = stats + 512,  *sh1 = stats + 640;
  float* oscH = stats + 768,  *oshH = stats + 896;
  float* oscB = stats + 1024, *oshB = stats + 1152;
  int* offsA = (int*)base;                     base += (NN + 1) * 4;
  int* permA = (int*)base;                     base += (size_t)EE * 4;
  int* offsB = (int*)base;                     base += (EE + 1) * 4;
  int* permB = (int*)base;                     base += (size_t)AA * 4;
  int* curA  = (int*)base;                     base += (size_t)NN * 4;
  int* curB  = (int*)base;                     base += (size_t)EE * 4;
  short* Wt0 = (short*)base;                   base += 20 * 16384 * 2;  // [4 grp][5][n][k]
  short* Wt1 = (short*)base;                   base += 20 * 16384 * 2;
  short* Wt2 = (short*)base;                   base += 20 * 16384 * 2;
  short* Bt0 = (short*)base;                   base += 6 * 40960 * 2;   // [6][n][320]
  short* Bt1 = (short*)base;                   base += 6 * 40960 * 2;
  short* Bt2 = (short*)base;                   base += 6 * 40960 * 2;

  // ---- prep: weight transpose/split ----
  k_prep_w<<<5 * 128, 128, 0, stream>>>(W1_a, Wt0,              Wt1,              Wt2);
  k_prep_w<<<5 * 128, 128, 0, stream>>>(W2_a, Wt0 + 5 * 16384,  Wt1 + 5 * 16384,  Wt2 + 5 * 16384);
  k_prep_w<<<5 * 128, 128, 0, stream>>>(W1_g, Wt0 + 10 * 16384, Wt1 + 10 * 16384, Wt2 + 10 * 16384);
  k_prep_w<<<5 * 128, 128, 0, stream>>>(W2_g, Wt0 + 15 * 16384, Wt1 + 15 * 16384, Wt2 + 15 * 16384);
  k_prep_bond<<<6 * 128, 320, 0, stream>>>(bfW, btab, bfb, Bt0, Bt1, Bt2);

  // ---- CSR build ----
  hipMemsetAsync(curA, 0, NN * sizeof(int), stream);
  hipMemsetAsync(curB, 0, EE * sizeof(int), stream);
  k_count<<<(EE + 255) / 256, 256, 0, stream>>>(ei + EE, curA, EE);
  k_count<<<(AA + 255) / 256, 256, 0, stream>>>(eib + AA, curB, AA);
  k_scan<<<1, 1024, 0, stream>>>(curA, offsA, NN, EE);
  k_scan<<<1, 1024, 0, stream>>>(curB, offsB, EE, AA);
  hipMemcpyAsync(curA, offsA, NN * sizeof(int), hipMemcpyDeviceToDevice, stream);
  hipMemcpyAsync(curB, offsB, EE * sizeof(int), hipMemcpyDeviceToDevice, stream);
  k_fill<<<(EE + 255) / 256, 256, 0, stream>>>(ei + EE, curA, permA, EE);
  k_fill<<<(AA + 255) / 256, 256, 0, stream>>>(eib + AA, curB, permB, AA);

  // ---- initial embeddings ----
  k_atom_embed<<<NN, 128, 0, stream>>>(x_atom, atab, hA0);
  k_bond_mfma<<<(EE + 127) / 128, 256, 0, stream>>>(xf, eai, Bt0, Bt1, Bt2, hB0);

  const int gA = (NN + 127) / 128, gB = (EE + 127) / 128;
  float* hA_cur = hA0;
  float* hB_cur = hB0;
  for (int l = 0; l < LL; ++l) {
    float* hA_nxt = (l & 1) ? hA0 : out_a;
    float* hB_nxt = (l & 1) ? hB0 : out_b;
    const bool obn = (l < LL - 1);
    size_t o1a = (size_t)l * 16384, o2a = (size_t)(5 + l) * 16384;
    size_t o1g = (size_t)(10 + l) * 16384, o2g = (size_t)(15 + l) * 16384;

    // ---- atom GIN conv ----
    if (l == 0)
      k_atom_gather<false><<<NN / 4, 256, 0, stream>>>(
          offsA, permA, ei, hA_cur, hB_cur, nullptr, nullptr, nullptr, nullptr,
          eps_a + l, preB);
    else
      k_atom_gather<true><<<NN / 4, 256, 0, stream>>>(
          offsA, permA, ei, hA_cur, hB_cur, oscH, oshH, oscB, oshB,
          eps_a + l, preB);
    hipMemsetAsync(stats, 0, 512 * sizeof(float), stream);
    k_gemm_mfma<false, true><<<gA, 256, 0, stream>>>(
        preB, Wt0 + o1a, Wt1 + o1a, Wt2 + o1a,
        b1_a + l * DD, T, nullptr, nullptr, sum1, sq1, NN);
    k_bn_finalize<<<1, 128, 0, stream>>>(sum1, sq1, bng_a + l * DD, bnb_a + l * DD, sc1, sh1, 1.f / NN);
    if (obn) {
      k_gemm_mfma<true, true><<<gA, 256, 0, stream>>>(
          T, Wt0 + o2a, Wt1 + o2a, Wt2 + o2a,
          b2_a + l * DD, hA_nxt, sc1, sh1, sum2, sq2, NN);
      k_bn_finalize<<<1, 128, 0, stream>>>(sum2, sq2, obng_a + l * DD, obnb_a + l * DD, oscH, oshH, 1.f / NN);
    } else {
      k_gemm_mfma<true, false><<<gA, 256, 0, stream>>>(
          T, Wt0 + o2a, Wt1 + o2a, Wt2 + o2a,
          b2_a + l * DD, hA_nxt, sc1, sh1, nullptr, nullptr, NN);
    }

    // ---- bond GIN conv ----
    k_bond_mfma<<<gB, 256, 0, stream>>>(
        xf, eai, Bt0 + (size_t)(l + 1) * 40960, Bt1 + (size_t)(l + 1) * 40960,
        Bt2 + (size_t)(l + 1) * 40960, T);
    k_angle_gather<<<EE / 4, 256, 0, stream>>>(
        offsB, permB, eib, xba,
        Wang + (size_t)l * 32 * DD, bang + l * DD,
        Wrest + (size_t)l * 5 * DD, brest + l * DD, T, eps_g + l, preB);
    hipMemsetAsync(stats, 0, 512 * sizeof(float), stream);
    k_gemm_mfma<false, true><<<gB, 256, 0, stream>>>(
        preB, Wt0 + o1g, Wt1 + o1g, Wt2 + o1g,
        b1_g + l * DD, T, nullptr, nullptr, sum1, sq1, EE);
    k_bn_finalize<<<1, 128, 0, stream>>>(sum1, sq1, bng_g + l * DD, bnb_g + l * DD, sc1, sh1, 1.f / EE);
    if (obn) {
      k_gemm_mfma<true, true><<<gB, 256, 0, stream>>>(
          T, Wt0 + o2g, Wt1 + o2g, Wt2 + o2g,
          b2_g + l * DD, hB_nxt, sc1, sh1, sum2, sq2, EE);
      k_bn_finalize<<<1, 128, 0, stream>>>(sum2, sq2, obng_b + l * DD, obnb_b + l * DD, oscB, oshB, 1.f / EE);
    } else {
      k_gemm_mfma<true, false><<<gB, 256, 0, stream>>>(
          T, Wt0 + o2g, Wt1 + o2g, Wt2 + o2g,
          b2_g + l * DD, hB_nxt, sc1, sh1, nullptr, nullptr, EE);
    }

    hA_cur = hA_nxt;
    hB_cur = hB_nxt;
  }
}